// Round 1
// baseline (5964.117 us; speedup 1.0000x reference)
//
#include <hip/hip_runtime.h>
#include <cstdint>

#define NN 100000
#define NE 1600000
#define HD 128
#define NL 4
#define NC 12
#define NG 512
#define BN_EPS 1e-5f

// ---------------- degree / normalization precompute ----------------

__global__ __launch_bounds__(256) void deg_kernel(const int* __restrict__ ei,
                                                  float* __restrict__ deg) {
    int e = blockIdx.x * 256 + threadIdx.x;
    if (e < NE) unsafeAtomicAdd(&deg[ei[NE + e]], 1.0f);
}

__global__ __launch_bounds__(256) void dinv_kernel(const float* __restrict__ deg,
                                                   float* __restrict__ dinv) {
    int i = blockIdx.x * 256 + threadIdx.x;
    if (i < NN) dinv[i] = rsqrtf(deg[i] + 1.0f);
}

__global__ __launch_bounds__(256) void coef_kernel(const int* __restrict__ ei,
                                                   const float* __restrict__ dinv,
                                                   float* __restrict__ coef) {
    int e = blockIdx.x * 256 + threadIdx.x;
    if (e < NE) coef[e] = dinv[ei[e]] * dinv[ei[NE + e]];
}

// ---------------- fp32 GEMM: [M,128] x [128,128] ----------------
// MODE 0: out0 = relu(acc + bias)          (input projection)
// MODE 1: out0 = acc (hw);  out1 = acc * dinv[row]^2   (conv + self-loop init)
template <int MODE>
__global__ __launch_bounds__(256) void gemm128(const float* __restrict__ A,
                                               const float* __restrict__ W,
                                               const float* __restrict__ bias,
                                               const float* __restrict__ dinv,
                                               float* __restrict__ out0,
                                               float* __restrict__ out1, int M) {
    __shared__ float Wl[32][128];   // K-quarter of W
    __shared__ float Al[64][132];   // row-major A tile (pad -> <=2-way conflicts)
    const int t = threadIdx.x;
    const int row0 = blockIdx.x * 64;
    const int tr = t >> 4;  // 0..15 -> rows tr*4 .. tr*4+3
    const int tc = t & 15;  // cols tc*4..+3 and 64+tc*4..+3

    float acc[4][8];
#pragma unroll
    for (int i = 0; i < 4; ++i)
#pragma unroll
        for (int j = 0; j < 8; ++j) acc[i][j] = 0.0f;

    for (int kc = 0; kc < 4; ++kc) {
        __syncthreads();
        // stage W quarter (k rows kc*32 .. +31), coalesced float4
#pragma unroll
        for (int rep = 0; rep < 4; ++rep) {
            int i = t + rep * 256;
            int k = i >> 5;
            int cq = i & 31;
            float4 v = *(const float4*)&W[(size_t)(kc * 32 + k) * HD + cq * 4];
            *(float4*)&Wl[k][cq * 4] = v;
        }
        // stage A tile K-quarter, row-major, coalesced float4
#pragma unroll
        for (int rep = 0; rep < 2; ++rep) {
            int i = t + rep * 256;
            int r = i >> 3;
            int kq = i & 7;
            int grow = row0 + r;
            float4 v = make_float4(0.f, 0.f, 0.f, 0.f);
            if (grow < M) v = *(const float4*)&A[(size_t)grow * HD + kc * 32 + kq * 4];
            *(float4*)&Al[r][kq * 4] = v;
        }
        __syncthreads();
#pragma unroll 4
        for (int k = 0; k < 32; ++k) {
            float av[4];
#pragma unroll
            for (int i = 0; i < 4; ++i) av[i] = Al[tr * 4 + i][k];
            float4 b0 = *(const float4*)&Wl[k][tc * 4];
            float4 b1 = *(const float4*)&Wl[k][64 + tc * 4];
            float bv[8] = {b0.x, b0.y, b0.z, b0.w, b1.x, b1.y, b1.z, b1.w};
#pragma unroll
            for (int i = 0; i < 4; ++i)
#pragma unroll
                for (int j = 0; j < 8; ++j) acc[i][j] = fmaf(av[i], bv[j], acc[i][j]);
        }
    }

#pragma unroll
    for (int i = 0; i < 4; ++i) {
        int grow = row0 + tr * 4 + i;
        if (grow < M) {
            size_t base = (size_t)grow * HD;
            if (MODE == 0) {
                float4 o0, o1;
                o0.x = fmaxf(acc[i][0] + bias[tc * 4 + 0], 0.f);
                o0.y = fmaxf(acc[i][1] + bias[tc * 4 + 1], 0.f);
                o0.z = fmaxf(acc[i][2] + bias[tc * 4 + 2], 0.f);
                o0.w = fmaxf(acc[i][3] + bias[tc * 4 + 3], 0.f);
                o1.x = fmaxf(acc[i][4] + bias[64 + tc * 4 + 0], 0.f);
                o1.y = fmaxf(acc[i][5] + bias[64 + tc * 4 + 1], 0.f);
                o1.z = fmaxf(acc[i][6] + bias[64 + tc * 4 + 2], 0.f);
                o1.w = fmaxf(acc[i][7] + bias[64 + tc * 4 + 3], 0.f);
                *(float4*)&out0[base + tc * 4] = o0;
                *(float4*)&out0[base + 64 + tc * 4] = o1;
            } else {
                float dd = dinv[grow];
                dd = dd * dd;
                float4 h0 = {acc[i][0], acc[i][1], acc[i][2], acc[i][3]};
                float4 h1 = {acc[i][4], acc[i][5], acc[i][6], acc[i][7]};
                *(float4*)&out0[base + tc * 4] = h0;
                *(float4*)&out0[base + 64 + tc * 4] = h1;
                float4 s0 = {h0.x * dd, h0.y * dd, h0.z * dd, h0.w * dd};
                float4 s1 = {h1.x * dd, h1.y * dd, h1.z * dd, h1.w * dd};
                *(float4*)&out1[base + tc * 4] = s0;
                *(float4*)&out1[base + 64 + tc * 4] = s1;
            }
        }
    }
}

// ---------------- edge scatter: agg[dst] += hw[src] * coef ----------------
__global__ __launch_bounds__(256) void edge_kernel(const int* __restrict__ ei,
                                                   const float* __restrict__ coef,
                                                   const float* __restrict__ hw,
                                                   float* __restrict__ agg) {
    int gid = blockIdx.x * 256 + threadIdx.x;
    int lane = gid & 63;
    int wid = gid >> 6;
    int nw = (gridDim.x * 256) >> 6;
    for (int e = wid; e < NE; e += nw) {
        int s = ei[e];
        int d = ei[NE + e];
        float cf = coef[e];
        float2 v = *(const float2*)&hw[(size_t)s * HD + lane * 2];
        unsafeAtomicAdd(&agg[(size_t)d * HD + lane * 2 + 0], v.x * cf);
        unsafeAtomicAdd(&agg[(size_t)d * HD + lane * 2 + 1], v.y * cf);
    }
}

// ---------------- BN + ReLU (in-place), conv bias folded in ----------------
__global__ __launch_bounds__(256) void bn_relu_kernel(float* __restrict__ agg,
                                                      const float* __restrict__ cb,
                                                      const float* __restrict__ gam,
                                                      const float* __restrict__ bet,
                                                      const float* __restrict__ mu,
                                                      const float* __restrict__ var) {
    int idx = blockIdx.x * 256 + threadIdx.x;  // over NN*32 float4 groups
    size_t base = (size_t)idx * 4;
    int c4 = (idx & 31) * 4;
    float4 v = *(const float4*)&agg[base];
    float o[4] = {v.x, v.y, v.z, v.w};
#pragma unroll
    for (int j = 0; j < 4; ++j) {
        int c = c4 + j;
        float a = gam[c] * rsqrtf(var[c] + BN_EPS);
        float val = (o[j] + cb[c] - mu[c]) * a + bet[c];
        o[j] = fmaxf(val, 0.f);
    }
    float4 w = {o[0], o[1], o[2], o[3]};
    *(float4*)&agg[base] = w;
}

// ---------------- global mean pool (atomics) ----------------
__global__ __launch_bounds__(256) void pool_kernel(const float* __restrict__ h,
                                                   const int* __restrict__ batch,
                                                   float* __restrict__ g,
                                                   float* __restrict__ cnt) {
    int gid = blockIdx.x * 256 + threadIdx.x;
    int lane = gid & 63;
    int wid = gid >> 6;
    int nw = (gridDim.x * 256) >> 6;
    for (int i = wid; i < NN; i += nw) {
        int b = batch[i];
        float2 v = *(const float2*)&h[(size_t)i * HD + lane * 2];
        unsafeAtomicAdd(&g[(size_t)b * HD + lane * 2 + 0], v.x);
        unsafeAtomicAdd(&g[(size_t)b * HD + lane * 2 + 1], v.y);
        if (lane == 0) unsafeAtomicAdd(&cnt[b], 1.0f);
    }
}

// ---------------- per-graph MLP head (normalize fused) ----------------
__global__ __launch_bounds__(64) void mlp_kernel(const float* __restrict__ g,
                                                 const float* __restrict__ cnt,
                                                 const float* __restrict__ fc1w,
                                                 const float* __restrict__ fc1b,
                                                 const float* __restrict__ fc2w,
                                                 const float* __restrict__ fc2b,
                                                 float* __restrict__ out) {
    __shared__ float gr[128];
    __shared__ float f1[64];
    int b = blockIdx.x, t = threadIdx.x;
    float inv = 1.0f / fmaxf(cnt[b], 1.0f);
    gr[t] = g[(size_t)b * HD + t] * inv;
    gr[t + 64] = g[(size_t)b * HD + 64 + t] * inv;
    __syncthreads();
    float acc = fc1b[t];
#pragma unroll 8
    for (int k = 0; k < 128; ++k) acc = fmaf(gr[k], fc1w[k * 64 + t], acc);
    f1[t] = fmaxf(acc, 0.f);
    __syncthreads();
    if (t < NC) {
        float a2 = fc2b[t];
#pragma unroll 8
        for (int k = 0; k < 64; ++k) a2 = fmaf(f1[k], fc2w[k * NC + t], a2);
        out[b * NC + t] = a2;
    }
    if (b == 0 && t == 63) out[NG * NC] = 0.0f;  // aux scalar output
}

// ---------------- launch ----------------
extern "C" void kernel_launch(void* const* d_in, const int* in_sizes, int n_in,
                              void* d_out, int out_size, void* d_ws, size_t ws_size,
                              hipStream_t stream) {
    const float* x      = (const float*)d_in[0];
    const int*   ei     = (const int*)d_in[1];
    const int*   batch  = (const int*)d_in[2];
    const float* w_in   = (const float*)d_in[3];
    const float* b_in   = (const float*)d_in[4];
    const float* conv_w = (const float*)d_in[5];
    const float* conv_b = (const float*)d_in[6];
    const float* gam    = (const float*)d_in[7];
    const float* bet    = (const float*)d_in[8];
    const float* mu     = (const float*)d_in[9];
    const float* var    = (const float*)d_in[10];
    const float* fc1w   = (const float*)d_in[11];
    const float* fc1b   = (const float*)d_in[12];
    const float* fc2w   = (const float*)d_in[13];
    const float* fc2b   = (const float*)d_in[14];
    float* out = (float*)d_out;

    size_t NH = (size_t)NN * HD;
    float* bufA = (float*)d_ws;
    float* bufB = bufA + NH;
    float* bufC = bufB + NH;
    float* deg  = bufC + NH;
    float* dinv = deg + NN;
    float* coef = dinv + NN;
    float* g    = coef + NE;
    float* cnt  = g + (size_t)NG * HD;

    hipMemsetAsync(deg, 0, NN * sizeof(float), stream);
    hipMemsetAsync(g, 0, (NG * HD + NG) * sizeof(float), stream);

    deg_kernel<<<(NE + 255) / 256, 256, 0, stream>>>(ei, deg);
    dinv_kernel<<<(NN + 255) / 256, 256, 0, stream>>>(deg, dinv);
    coef_kernel<<<(NE + 255) / 256, 256, 0, stream>>>(ei, dinv, coef);

    int gblocks = (NN + 63) / 64;
    gemm128<0><<<gblocks, 256, 0, stream>>>(x, w_in, b_in, nullptr, bufA, nullptr, NN);

    float* h = bufA;
    float* hw = bufB;
    float* agg = bufC;
    for (int l = 0; l < NL; ++l) {
        gemm128<1><<<gblocks, 256, 0, stream>>>(h, conv_w + (size_t)l * HD * HD,
                                                nullptr, dinv, hw, agg, NN);
        edge_kernel<<<2048, 256, 0, stream>>>(ei, coef, hw, agg);
        bn_relu_kernel<<<(NN * 32) / 256, 256, 0, stream>>>(
            agg, conv_b + l * HD, gam + l * HD, bet + l * HD, mu + l * HD, var + l * HD);
        float* nh = agg;
        float* nhw = h;
        float* nagg = hw;
        h = nh; hw = nhw; agg = nagg;
    }

    pool_kernel<<<1024, 256, 0, stream>>>(h, batch, g, cnt);
    mlp_kernel<<<NG, 64, 0, stream>>>(g, cnt, fc1w, fc1b, fc2w, fc2b, out);
}

// Round 2
// 1691.459 us; speedup vs baseline: 3.5260x; 3.5260x over previous
//
#include <hip/hip_runtime.h>
#include <cstdint>

#define NN 100000
#define NE 1600000
#define HD 128
#define NL 4
#define NC 12
#define NG 512
#define BN_EPS 1e-5f

// ---------------- degree / normalization precompute ----------------

__global__ __launch_bounds__(256) void deg_kernel(const int* __restrict__ ei,
                                                  float* __restrict__ deg) {
    int e = blockIdx.x * 256 + threadIdx.x;
    if (e < NE) unsafeAtomicAdd(&deg[ei[NE + e]], 1.0f);
}

__global__ __launch_bounds__(256) void dinv_kernel(const float* __restrict__ deg,
                                                   float* __restrict__ dinv) {
    int i = blockIdx.x * 256 + threadIdx.x;
    if (i < NN) dinv[i] = rsqrtf(deg[i] + 1.0f);
}

// one-block exclusive scan of (int)deg -> offsets[NN+1]; also init cursor
__global__ __launch_bounds__(1024) void scan_kernel(const float* __restrict__ deg,
                                                    int* __restrict__ offsets,
                                                    int* __restrict__ cursor) {
    __shared__ int bs[1024];
    const int t = threadIdx.x;
    const int CH = (NN + 1023) / 1024;  // 98
    int start = t * CH;
    int end = min(start + CH, NN);
    int s = 0;
    for (int i = start; i < end; ++i) s += (int)deg[i];
    bs[t] = s;
    __syncthreads();
    // Hillis-Steele inclusive scan
    for (int off = 1; off < 1024; off <<= 1) {
        int v = bs[t];
        int add = (t >= off) ? bs[t - off] : 0;
        __syncthreads();
        bs[t] = v + add;
        __syncthreads();
    }
    int off = (t == 0) ? 0 : bs[t - 1];  // exclusive prefix for this chunk
    for (int i = start; i < end; ++i) {
        offsets[i] = off;
        cursor[i] = off;
        off += (int)deg[i];
    }
    if (t == 1023) offsets[NN] = off;  // == NE
}

// fill CSR: csr_src[pos]=src, csr_coef[pos]=dinv[src]*dinv[dst]
__global__ __launch_bounds__(256) void fill_kernel(const int* __restrict__ ei,
                                                   const float* __restrict__ dinv,
                                                   int* __restrict__ cursor,
                                                   int* __restrict__ csr_src,
                                                   float* __restrict__ csr_coef) {
    int e = blockIdx.x * 256 + threadIdx.x;
    if (e < NE) {
        int s = ei[e];
        int d = ei[NE + e];
        int pos = atomicAdd(&cursor[d], 1);
        csr_src[pos] = s;
        csr_coef[pos] = dinv[s] * dinv[d];
    }
}

// per-layer BN fold: val = acc*A + B with A=gam*rsqrt(var+eps), B=(cb-mu)*A+bet
__global__ __launch_bounds__(128) void bnpre_kernel(const float* __restrict__ cb,
                                                    const float* __restrict__ gam,
                                                    const float* __restrict__ bet,
                                                    const float* __restrict__ mu,
                                                    const float* __restrict__ var,
                                                    float* __restrict__ bnA,
                                                    float* __restrict__ bnB) {
    int i = blockIdx.x * 128 + threadIdx.x;  // over NL*HD
    float a = gam[i] * rsqrtf(var[i] + BN_EPS);
    bnA[i] = a;
    bnB[i] = (cb[i] - mu[i]) * a + bet[i];
}

// ---------------- fp32 GEMM: [M,128] x [128,128] ----------------
// MODE 0: out = relu(acc + bias)   MODE 1: out = acc
template <int MODE>
__global__ __launch_bounds__(256) void gemm128(const float* __restrict__ A,
                                               const float* __restrict__ W,
                                               const float* __restrict__ bias,
                                               float* __restrict__ out0, int M) {
    __shared__ float Wl[32][128];
    __shared__ float Al[64][132];
    const int t = threadIdx.x;
    const int row0 = blockIdx.x * 64;
    const int tr = t >> 4;
    const int tc = t & 15;

    float acc[4][8];
#pragma unroll
    for (int i = 0; i < 4; ++i)
#pragma unroll
        for (int j = 0; j < 8; ++j) acc[i][j] = 0.0f;

    for (int kc = 0; kc < 4; ++kc) {
        __syncthreads();
#pragma unroll
        for (int rep = 0; rep < 4; ++rep) {
            int i = t + rep * 256;
            int k = i >> 5;
            int cq = i & 31;
            float4 v = *(const float4*)&W[(size_t)(kc * 32 + k) * HD + cq * 4];
            *(float4*)&Wl[k][cq * 4] = v;
        }
#pragma unroll
        for (int rep = 0; rep < 2; ++rep) {
            int i = t + rep * 256;
            int r = i >> 3;
            int kq = i & 7;
            int grow = row0 + r;
            float4 v = make_float4(0.f, 0.f, 0.f, 0.f);
            if (grow < M) v = *(const float4*)&A[(size_t)grow * HD + kc * 32 + kq * 4];
            *(float4*)&Al[r][kq * 4] = v;
        }
        __syncthreads();
#pragma unroll 4
        for (int k = 0; k < 32; ++k) {
            float av[4];
#pragma unroll
            for (int i = 0; i < 4; ++i) av[i] = Al[tr * 4 + i][k];
            float4 b0 = *(const float4*)&Wl[k][tc * 4];
            float4 b1 = *(const float4*)&Wl[k][64 + tc * 4];
            float bv[8] = {b0.x, b0.y, b0.z, b0.w, b1.x, b1.y, b1.z, b1.w};
#pragma unroll
            for (int i = 0; i < 4; ++i)
#pragma unroll
                for (int j = 0; j < 8; ++j) acc[i][j] = fmaf(av[i], bv[j], acc[i][j]);
        }
    }

#pragma unroll
    for (int i = 0; i < 4; ++i) {
        int grow = row0 + tr * 4 + i;
        if (grow < M) {
            size_t base = (size_t)grow * HD;
            float4 o0, o1;
            if (MODE == 0) {
                o0.x = fmaxf(acc[i][0] + bias[tc * 4 + 0], 0.f);
                o0.y = fmaxf(acc[i][1] + bias[tc * 4 + 1], 0.f);
                o0.z = fmaxf(acc[i][2] + bias[tc * 4 + 2], 0.f);
                o0.w = fmaxf(acc[i][3] + bias[tc * 4 + 3], 0.f);
                o1.x = fmaxf(acc[i][4] + bias[64 + tc * 4 + 0], 0.f);
                o1.y = fmaxf(acc[i][5] + bias[64 + tc * 4 + 1], 0.f);
                o1.z = fmaxf(acc[i][6] + bias[64 + tc * 4 + 2], 0.f);
                o1.w = fmaxf(acc[i][7] + bias[64 + tc * 4 + 3], 0.f);
            } else {
                o0 = make_float4(acc[i][0], acc[i][1], acc[i][2], acc[i][3]);
                o1 = make_float4(acc[i][4], acc[i][5], acc[i][6], acc[i][7]);
            }
            *(float4*)&out0[base + tc * 4] = o0;
            *(float4*)&out0[base + 64 + tc * 4] = o1;
        }
    }
}

// ---------------- pull aggregation + BN + ReLU (one wave per node) --------
__global__ __launch_bounds__(256) void agg_kernel(const int* __restrict__ offsets,
                                                  const int* __restrict__ csr_src,
                                                  const float* __restrict__ csr_coef,
                                                  const float* __restrict__ dinv,
                                                  const float* __restrict__ hw,
                                                  const float* __restrict__ bnA,
                                                  const float* __restrict__ bnB,
                                                  float* __restrict__ hout) {
    int w = (blockIdx.x * 256 + threadIdx.x) >> 6;
    int lane = threadIdx.x & 63;
    if (w >= NN) return;
    int c = lane * 2;
    int b0 = offsets[w];
    int b1 = offsets[w + 1];
    float dd = dinv[w];
    dd *= dd;
    float2 v = *(const float2*)&hw[(size_t)w * HD + c];
    float ax = dd * v.x, ay = dd * v.y;
    for (int j = b0; j < b1; ++j) {
        int s = csr_src[j];
        float cf = csr_coef[j];
        float2 u = *(const float2*)&hw[(size_t)s * HD + c];
        ax = fmaf(cf, u.x, ax);
        ay = fmaf(cf, u.y, ay);
    }
    float rx = fmaxf(fmaf(ax, bnA[c], bnB[c]), 0.f);
    float ry = fmaxf(fmaf(ay, bnA[c + 1], bnB[c + 1]), 0.f);
    *(float2*)&hout[(size_t)w * HD + c] = make_float2(rx, ry);
}

// ---------------- global mean pool (atomics) ----------------
__global__ __launch_bounds__(256) void pool_kernel(const float* __restrict__ h,
                                                   const int* __restrict__ batch,
                                                   float* __restrict__ g,
                                                   float* __restrict__ cnt) {
    int gid = blockIdx.x * 256 + threadIdx.x;
    int lane = gid & 63;
    int wid = gid >> 6;
    int nw = (gridDim.x * 256) >> 6;
    for (int i = wid; i < NN; i += nw) {
        int b = batch[i];
        float2 v = *(const float2*)&h[(size_t)i * HD + lane * 2];
        unsafeAtomicAdd(&g[(size_t)b * HD + lane * 2 + 0], v.x);
        unsafeAtomicAdd(&g[(size_t)b * HD + lane * 2 + 1], v.y);
        if (lane == 0) unsafeAtomicAdd(&cnt[b], 1.0f);
    }
}

// ---------------- per-graph MLP head (normalize fused) ----------------
__global__ __launch_bounds__(64) void mlp_kernel(const float* __restrict__ g,
                                                 const float* __restrict__ cnt,
                                                 const float* __restrict__ fc1w,
                                                 const float* __restrict__ fc1b,
                                                 const float* __restrict__ fc2w,
                                                 const float* __restrict__ fc2b,
                                                 float* __restrict__ out) {
    __shared__ float gr[128];
    __shared__ float f1[64];
    int b = blockIdx.x, t = threadIdx.x;
    float inv = 1.0f / fmaxf(cnt[b], 1.0f);
    gr[t] = g[(size_t)b * HD + t] * inv;
    gr[t + 64] = g[(size_t)b * HD + 64 + t] * inv;
    __syncthreads();
    float acc = fc1b[t];
#pragma unroll 8
    for (int k = 0; k < 128; ++k) acc = fmaf(gr[k], fc1w[k * 64 + t], acc);
    f1[t] = fmaxf(acc, 0.f);
    __syncthreads();
    if (t < NC) {
        float a2 = fc2b[t];
#pragma unroll 8
        for (int k = 0; k < 64; ++k) a2 = fmaf(f1[k], fc2w[k * NC + t], a2);
        out[b * NC + t] = a2;
    }
    if (b == 0 && t == 63) out[NG * NC] = 0.0f;  // aux scalar output
}

// ---------------- launch ----------------
extern "C" void kernel_launch(void* const* d_in, const int* in_sizes, int n_in,
                              void* d_out, int out_size, void* d_ws, size_t ws_size,
                              hipStream_t stream) {
    const float* x      = (const float*)d_in[0];
    const int*   ei     = (const int*)d_in[1];
    const int*   batch  = (const int*)d_in[2];
    const float* w_in   = (const float*)d_in[3];
    const float* b_in   = (const float*)d_in[4];
    const float* conv_w = (const float*)d_in[5];
    const float* conv_b = (const float*)d_in[6];
    const float* gam    = (const float*)d_in[7];
    const float* bet    = (const float*)d_in[8];
    const float* mu     = (const float*)d_in[9];
    const float* var    = (const float*)d_in[10];
    const float* fc1w   = (const float*)d_in[11];
    const float* fc1b   = (const float*)d_in[12];
    const float* fc2w   = (const float*)d_in[13];
    const float* fc2b   = (const float*)d_in[14];
    float* out = (float*)d_out;

    size_t NH = (size_t)NN * HD;
    float* bufA = (float*)d_ws;               // h
    float* bufB = bufA + NH;                  // hw
    float* deg  = bufB + NH;
    float* dinv = deg + NN;
    float* bnA  = dinv + NN;                  // NL*HD
    float* bnB  = bnA + NL * HD;              // NL*HD
    float* g    = bnB + NL * HD;              // NG*HD
    float* cnt  = g + (size_t)NG * HD;        // NG
    int* offsets  = (int*)(cnt + NG);         // NN+1
    int* cursor   = offsets + NN + 1;         // NN
    int* csr_src  = cursor + NN;              // NE
    float* csr_coef = (float*)(csr_src + NE); // NE

    hipMemsetAsync(deg, 0, NN * sizeof(float), stream);
    hipMemsetAsync(g, 0, (NG * HD + NG) * sizeof(float), stream);

    deg_kernel<<<(NE + 255) / 256, 256, 0, stream>>>(ei, deg);
    dinv_kernel<<<(NN + 255) / 256, 256, 0, stream>>>(deg, dinv);
    scan_kernel<<<1, 1024, 0, stream>>>(deg, offsets, cursor);
    fill_kernel<<<(NE + 255) / 256, 256, 0, stream>>>(ei, dinv, cursor, csr_src, csr_coef);
    bnpre_kernel<<<NL, 128, 0, stream>>>(conv_b, gam, bet, mu, var, bnA, bnB);

    int gblocks = (NN + 63) / 64;
    gemm128<0><<<gblocks, 256, 0, stream>>>(x, w_in, b_in, bufA, NN);

    for (int l = 0; l < NL; ++l) {
        gemm128<1><<<gblocks, 256, 0, stream>>>(bufA, conv_w + (size_t)l * HD * HD,
                                                nullptr, bufB, NN);
        agg_kernel<<<(NN * 64 + 255) / 256, 256, 0, stream>>>(
            offsets, csr_src, csr_coef, dinv, bufB, bnA + l * HD, bnB + l * HD, bufA);
    }

    pool_kernel<<<1024, 256, 0, stream>>>(bufA, batch, g, cnt);
    mlp_kernel<<<NG, 64, 0, stream>>>(g, cnt, fc1w, fc1b, fc2w, fc2b, out);
}

// Round 3
// 1479.461 us; speedup vs baseline: 4.0313x; 1.1433x over previous
//
#include <hip/hip_runtime.h>
#include <cstdint>

#define NN 100000
#define NE 1600000
#define HD 128
#define NL 4
#define NC 12
#define NG 512
#define BN_EPS 1e-5f

// ---------------- degree / normalization precompute ----------------

__global__ __launch_bounds__(256) void deg_kernel(const int* __restrict__ ei,
                                                  float* __restrict__ deg) {
    int e = blockIdx.x * 256 + threadIdx.x;
    if (e < NE) unsafeAtomicAdd(&deg[ei[NE + e]], 1.0f);
}

__global__ __launch_bounds__(256) void dinv_kernel(const float* __restrict__ deg,
                                                   float* __restrict__ dinv) {
    int i = blockIdx.x * 256 + threadIdx.x;
    if (i < NN) dinv[i] = rsqrtf(deg[i] + 1.0f);
}

// one-block exclusive scan of (int)deg -> offsets[NN+1]; also init cursor
__global__ __launch_bounds__(1024) void scan_kernel(const float* __restrict__ deg,
                                                    int* __restrict__ offsets,
                                                    int* __restrict__ cursor) {
    __shared__ int bs[1024];
    const int t = threadIdx.x;
    const int CH = (NN + 1023) / 1024;  // 98
    int start = t * CH;
    int end = min(start + CH, NN);
    int s = 0;
    for (int i = start; i < end; ++i) s += (int)deg[i];
    bs[t] = s;
    __syncthreads();
    for (int off = 1; off < 1024; off <<= 1) {
        int v = bs[t];
        int add = (t >= off) ? bs[t - off] : 0;
        __syncthreads();
        bs[t] = v + add;
        __syncthreads();
    }
    int off = (t == 0) ? 0 : bs[t - 1];
    for (int i = start; i < end; ++i) {
        offsets[i] = off;
        cursor[i] = off;
        off += (int)deg[i];
    }
    if (t == 1023) offsets[NN] = off;  // == NE
}

// fill CSR: csr_src[pos]=src, csr_coef[pos]=dinv[src]*dinv[dst]
__global__ __launch_bounds__(256) void fill_kernel(const int* __restrict__ ei,
                                                   const float* __restrict__ dinv,
                                                   int* __restrict__ cursor,
                                                   int* __restrict__ csr_src,
                                                   float* __restrict__ csr_coef) {
    int e = blockIdx.x * 256 + threadIdx.x;
    if (e < NE) {
        int s = ei[e];
        int d = ei[NE + e];
        int pos = atomicAdd(&cursor[d], 1);
        csr_src[pos] = s;
        csr_coef[pos] = dinv[s] * dinv[d];
    }
}

// per-layer BN fold: val = acc*A + B
__global__ __launch_bounds__(128) void bnpre_kernel(const float* __restrict__ cb,
                                                    const float* __restrict__ gam,
                                                    const float* __restrict__ bet,
                                                    const float* __restrict__ mu,
                                                    const float* __restrict__ var,
                                                    float* __restrict__ bnA,
                                                    float* __restrict__ bnB) {
    int i = blockIdx.x * 128 + threadIdx.x;  // over NL*HD
    float a = gam[i] * rsqrtf(var[i] + BN_EPS);
    bnA[i] = a;
    bnB[i] = (cb[i] - mu[i]) * a + bet[i];
}

// graph boundaries: goff[g] = first node with batch >= g (batch is sorted)
__global__ __launch_bounds__(64) void gboff_kernel(const int* __restrict__ batch,
                                                   int* __restrict__ goff) {
    int g = blockIdx.x * 64 + threadIdx.x;
    if (g > NG) return;
    int lo = 0, hi = NN;
    while (lo < hi) {
        int mid = (lo + hi) >> 1;
        if (batch[mid] < g) lo = mid + 1; else hi = mid;
    }
    goff[g] = lo;
}

// ---------------- fp32 GEMM: [M,128] x [128,128] ----------------
// MODE 0: out = relu(acc + bias)   MODE 1: out = acc
template <int MODE>
__global__ __launch_bounds__(256) void gemm128(const float* __restrict__ A,
                                               const float* __restrict__ W,
                                               const float* __restrict__ bias,
                                               float* __restrict__ out0, int M) {
    __shared__ float Wl[32][128];
    __shared__ float Al[64][132];
    const int t = threadIdx.x;
    const int row0 = blockIdx.x * 64;
    const int tr = t >> 4;
    const int tc = t & 15;

    float acc[4][8];
#pragma unroll
    for (int i = 0; i < 4; ++i)
#pragma unroll
        for (int j = 0; j < 8; ++j) acc[i][j] = 0.0f;

    for (int kc = 0; kc < 4; ++kc) {
        __syncthreads();
#pragma unroll
        for (int rep = 0; rep < 4; ++rep) {
            int i = t + rep * 256;
            int k = i >> 5;
            int cq = i & 31;
            float4 v = *(const float4*)&W[(size_t)(kc * 32 + k) * HD + cq * 4];
            *(float4*)&Wl[k][cq * 4] = v;
        }
#pragma unroll
        for (int rep = 0; rep < 2; ++rep) {
            int i = t + rep * 256;
            int r = i >> 3;
            int kq = i & 7;
            int grow = row0 + r;
            float4 v = make_float4(0.f, 0.f, 0.f, 0.f);
            if (grow < M) v = *(const float4*)&A[(size_t)grow * HD + kc * 32 + kq * 4];
            *(float4*)&Al[r][kq * 4] = v;
        }
        __syncthreads();
#pragma unroll 2
        for (int k4 = 0; k4 < 32; k4 += 4) {
            float4 a4[4];
#pragma unroll
            for (int i = 0; i < 4; ++i) a4[i] = *(const float4*)&Al[tr * 4 + i][k4];
#pragma unroll
            for (int kk = 0; kk < 4; ++kk) {
                float4 b0 = *(const float4*)&Wl[k4 + kk][tc * 4];
                float4 b1 = *(const float4*)&Wl[k4 + kk][64 + tc * 4];
                float bv[8] = {b0.x, b0.y, b0.z, b0.w, b1.x, b1.y, b1.z, b1.w};
#pragma unroll
                for (int i = 0; i < 4; ++i) {
                    float av = ((const float*)&a4[i])[kk];
#pragma unroll
                    for (int j = 0; j < 8; ++j) acc[i][j] = fmaf(av, bv[j], acc[i][j]);
                }
            }
        }
    }

#pragma unroll
    for (int i = 0; i < 4; ++i) {
        int grow = row0 + tr * 4 + i;
        if (grow < M) {
            size_t base = (size_t)grow * HD;
            float4 o0, o1;
            if (MODE == 0) {
                o0.x = fmaxf(acc[i][0] + bias[tc * 4 + 0], 0.f);
                o0.y = fmaxf(acc[i][1] + bias[tc * 4 + 1], 0.f);
                o0.z = fmaxf(acc[i][2] + bias[tc * 4 + 2], 0.f);
                o0.w = fmaxf(acc[i][3] + bias[tc * 4 + 3], 0.f);
                o1.x = fmaxf(acc[i][4] + bias[64 + tc * 4 + 0], 0.f);
                o1.y = fmaxf(acc[i][5] + bias[64 + tc * 4 + 1], 0.f);
                o1.z = fmaxf(acc[i][6] + bias[64 + tc * 4 + 2], 0.f);
                o1.w = fmaxf(acc[i][7] + bias[64 + tc * 4 + 3], 0.f);
            } else {
                o0 = make_float4(acc[i][0], acc[i][1], acc[i][2], acc[i][3]);
                o1 = make_float4(acc[i][4], acc[i][5], acc[i][6], acc[i][7]);
            }
            *(float4*)&out0[base + tc * 4] = o0;
            *(float4*)&out0[base + 64 + tc * 4] = o1;
        }
    }
}

// ---------------- pull aggregation + BN + ReLU (one wave per node) --------
__global__ __launch_bounds__(256) void agg_kernel(const int* __restrict__ offsets,
                                                  const int* __restrict__ csr_src,
                                                  const float* __restrict__ csr_coef,
                                                  const float* __restrict__ dinv,
                                                  const float* __restrict__ hw,
                                                  const float* __restrict__ bnA,
                                                  const float* __restrict__ bnB,
                                                  float* __restrict__ hout) {
    int w = (blockIdx.x * 256 + threadIdx.x) >> 6;
    int lane = threadIdx.x & 63;
    if (w >= NN) return;
    int c = lane * 2;
    int b0 = offsets[w];
    int b1 = offsets[w + 1];
    float dd = dinv[w];
    dd *= dd;
    float2 v = *(const float2*)&hw[(size_t)w * HD + c];
    float ax = dd * v.x, ay = dd * v.y;
    for (int j = b0; j < b1; ++j) {
        int s = csr_src[j];
        float cf = csr_coef[j];
        float2 u = *(const float2*)&hw[(size_t)s * HD + c];
        ax = fmaf(cf, u.x, ax);
        ay = fmaf(cf, u.y, ay);
    }
    float rx = fmaxf(fmaf(ax, bnA[c], bnB[c]), 0.f);
    float ry = fmaxf(fmaf(ay, bnA[c + 1], bnB[c + 1]), 0.f);
    *(float2*)&hout[(size_t)w * HD + c] = make_float2(rx, ry);
}

// ---------------- segmented mean pool (batch sorted -> contiguous) --------
__global__ __launch_bounds__(256) void pool_kernel(const float* __restrict__ h,
                                                   const int* __restrict__ goff,
                                                   float* __restrict__ g) {
    int b = blockIdx.x;
    int t = threadIdx.x;
    int c = t & 127;
    int half = t >> 7;  // 0 or 1
    int i0 = goff[b], i1 = goff[b + 1];
    float acc = 0.f;
    for (int i = i0 + half; i < i1; i += 2) acc += h[(size_t)i * HD + c];
    __shared__ float sh[256];
    sh[t] = acc;
    __syncthreads();
    if (half == 0) {
        float s = sh[c] + sh[128 + c];
        float invc = 1.0f / fmaxf((float)(i1 - i0), 1.0f);
        g[(size_t)b * HD + c] = s * invc;
    }
}

// ---------------- per-graph MLP head ----------------
__global__ __launch_bounds__(64) void mlp_kernel(const float* __restrict__ g,
                                                 const float* __restrict__ fc1w,
                                                 const float* __restrict__ fc1b,
                                                 const float* __restrict__ fc2w,
                                                 const float* __restrict__ fc2b,
                                                 float* __restrict__ out) {
    __shared__ float gr[128];
    __shared__ float f1[64];
    int b = blockIdx.x, t = threadIdx.x;
    gr[t] = g[(size_t)b * HD + t];
    gr[t + 64] = g[(size_t)b * HD + 64 + t];
    __syncthreads();
    float acc = fc1b[t];
#pragma unroll 8
    for (int k = 0; k < 128; ++k) acc = fmaf(gr[k], fc1w[k * 64 + t], acc);
    f1[t] = fmaxf(acc, 0.f);
    __syncthreads();
    if (t < NC) {
        float a2 = fc2b[t];
#pragma unroll 8
        for (int k = 0; k < 64; ++k) a2 = fmaf(f1[k], fc2w[k * NC + t], a2);
        out[b * NC + t] = a2;
    }
    if (b == 0 && t == 63) out[NG * NC] = 0.0f;  // aux scalar output
}

// ---------------- launch ----------------
extern "C" void kernel_launch(void* const* d_in, const int* in_sizes, int n_in,
                              void* d_out, int out_size, void* d_ws, size_t ws_size,
                              hipStream_t stream) {
    const float* x      = (const float*)d_in[0];
    const int*   ei     = (const int*)d_in[1];
    const int*   batch  = (const int*)d_in[2];
    const float* w_in   = (const float*)d_in[3];
    const float* b_in   = (const float*)d_in[4];
    const float* conv_w = (const float*)d_in[5];
    const float* conv_b = (const float*)d_in[6];
    const float* gam    = (const float*)d_in[7];
    const float* bet    = (const float*)d_in[8];
    const float* mu     = (const float*)d_in[9];
    const float* var    = (const float*)d_in[10];
    const float* fc1w   = (const float*)d_in[11];
    const float* fc1b   = (const float*)d_in[12];
    const float* fc2w   = (const float*)d_in[13];
    const float* fc2b   = (const float*)d_in[14];
    float* out = (float*)d_out;

    size_t NH = (size_t)NN * HD;
    float* bufA = (float*)d_ws;               // h
    float* bufB = bufA + NH;                  // hw
    float* deg  = bufB + NH;
    float* dinv = deg + NN;
    float* bnA  = dinv + NN;                  // NL*HD
    float* bnB  = bnA + NL * HD;              // NL*HD
    float* g    = bnB + NL * HD;              // NG*HD
    int* offsets  = (int*)(g + (size_t)NG * HD);  // NN+1
    int* cursor   = offsets + NN + 1;         // NN
    int* csr_src  = cursor + NN;              // NE
    float* csr_coef = (float*)(csr_src + NE); // NE
    int* goff     = (int*)(csr_coef + NE);    // NG+1

    hipMemsetAsync(deg, 0, NN * sizeof(float), stream);

    deg_kernel<<<(NE + 255) / 256, 256, 0, stream>>>(ei, deg);
    dinv_kernel<<<(NN + 255) / 256, 256, 0, stream>>>(deg, dinv);
    scan_kernel<<<1, 1024, 0, stream>>>(deg, offsets, cursor);
    fill_kernel<<<(NE + 255) / 256, 256, 0, stream>>>(ei, dinv, cursor, csr_src, csr_coef);
    bnpre_kernel<<<NL, 128, 0, stream>>>(conv_b, gam, bet, mu, var, bnA, bnB);
    gboff_kernel<<<(NG + 64) / 64, 64, 0, stream>>>(batch, goff);

    int gblocks = (NN + 63) / 64;
    gemm128<0><<<gblocks, 256, 0, stream>>>(x, w_in, b_in, bufA, NN);

    for (int l = 0; l < NL; ++l) {
        gemm128<1><<<gblocks, 256, 0, stream>>>(bufA, conv_w + (size_t)l * HD * HD,
                                                nullptr, bufB, NN);
        agg_kernel<<<(NN * 64 + 255) / 256, 256, 0, stream>>>(
            offsets, csr_src, csr_coef, dinv, bufB, bnA + l * HD, bnB + l * HD, bufA);
    }

    pool_kernel<<<NG, 256, 0, stream>>>(bufA, goff, g);
    mlp_kernel<<<NG, 64, 0, stream>>>(g, fc1w, fc1b, fc2w, fc2b, out);
}

// Round 4
// 1237.416 us; speedup vs baseline: 4.8198x; 1.1956x over previous
//
#include <hip/hip_runtime.h>
#include <cstdint>

#define NN 100000
#define NE 1600000
#define HD 128
#define NL 4
#define NC 12
#define NG 512
#define NB ((NN + 255) / 256)  // 391 scan blocks
#define BN_EPS 1e-5f

// ---------------- degree / normalization precompute ----------------

__global__ __launch_bounds__(256) void deg_kernel(const int* __restrict__ ei,
                                                  float* __restrict__ deg) {
    int e = blockIdx.x * 256 + threadIdx.x;
    if (e < NE) unsafeAtomicAdd(&deg[ei[NE + e]], 1.0f);
}

__global__ __launch_bounds__(256) void dinv_kernel(const float* __restrict__ deg,
                                                   float* __restrict__ dinv) {
    int i = blockIdx.x * 256 + threadIdx.x;
    if (i < NN) dinv[i] = rsqrtf(deg[i] + 1.0f);
}

// ---- parallel scan: A) per-block exclusive scan + block sums ----
__global__ __launch_bounds__(256) void scanA_kernel(const float* __restrict__ deg,
                                                    int* __restrict__ loc,
                                                    int* __restrict__ bsum) {
    __shared__ int sh[256];
    int t = threadIdx.x;
    int i = blockIdx.x * 256 + t;
    int v = (i < NN) ? (int)deg[i] : 0;
    sh[t] = v;
    __syncthreads();
    for (int off = 1; off < 256; off <<= 1) {
        int x = sh[t];
        int add = (t >= off) ? sh[t - off] : 0;
        __syncthreads();
        sh[t] = x + add;
        __syncthreads();
    }
    if (i < NN) loc[i] = sh[t] - v;  // exclusive within block
    if (t == 255) bsum[blockIdx.x] = sh[255];
}

// ---- B) scan the 391 block sums (one block) ----
__global__ __launch_bounds__(512) void scanB_kernel(int* __restrict__ bsum) {
    __shared__ int sh[512];
    int t = threadIdx.x;
    int v = (t < NB) ? bsum[t] : 0;
    sh[t] = v;
    __syncthreads();
    for (int off = 1; off < 512; off <<= 1) {
        int x = sh[t];
        int add = (t >= off) ? sh[t - off] : 0;
        __syncthreads();
        sh[t] = x + add;
        __syncthreads();
    }
    if (t < NB) bsum[t] = sh[t] - v;  // exclusive block prefix
}

// ---- C) combine -> offsets, cursor ----
__global__ __launch_bounds__(256) void scanC_kernel(const int* __restrict__ loc,
                                                    const int* __restrict__ bsum,
                                                    int* __restrict__ offsets,
                                                    int* __restrict__ cursor) {
    int i = blockIdx.x * 256 + threadIdx.x;
    if (i < NN) {
        int o = bsum[blockIdx.x] + loc[i];
        offsets[i] = o;
        cursor[i] = o;
    }
    if (i == 0) offsets[NN] = NE;
}

// fill CSR packed: csr[pos] = (bits(src), dinv[src]*dinv[dst])
__global__ __launch_bounds__(256) void fill_kernel(const int* __restrict__ ei,
                                                   const float* __restrict__ dinv,
                                                   int* __restrict__ cursor,
                                                   float2* __restrict__ csr) {
    int e = blockIdx.x * 256 + threadIdx.x;
    if (e < NE) {
        int s = ei[e];
        int d = ei[NE + e];
        int pos = atomicAdd(&cursor[d], 1);
        csr[pos] = make_float2(__int_as_float(s), dinv[s] * dinv[d]);
    }
}

// per-layer BN fold: val = acc*A + B
__global__ __launch_bounds__(128) void bnpre_kernel(const float* __restrict__ cb,
                                                    const float* __restrict__ gam,
                                                    const float* __restrict__ bet,
                                                    const float* __restrict__ mu,
                                                    const float* __restrict__ var,
                                                    float* __restrict__ bnA,
                                                    float* __restrict__ bnB) {
    int i = blockIdx.x * 128 + threadIdx.x;  // over NL*HD
    float a = gam[i] * rsqrtf(var[i] + BN_EPS);
    bnA[i] = a;
    bnB[i] = (cb[i] - mu[i]) * a + bet[i];
}

// graph boundaries: goff[g] = first node with batch >= g (batch is sorted)
__global__ __launch_bounds__(64) void gboff_kernel(const int* __restrict__ batch,
                                                   int* __restrict__ goff) {
    int g = blockIdx.x * 64 + threadIdx.x;
    if (g > NG) return;
    int lo = 0, hi = NN;
    while (lo < hi) {
        int mid = (lo + hi) >> 1;
        if (batch[mid] < g) lo = mid + 1; else hi = mid;
    }
    goff[g] = lo;
}

// ---------------- fp32 GEMM: [M,128] x [128,128] ----------------
// MODE 0: out = relu(acc + bias)   MODE 1: out = acc
template <int MODE>
__global__ __launch_bounds__(256) void gemm128(const float* __restrict__ A,
                                               const float* __restrict__ W,
                                               const float* __restrict__ bias,
                                               float* __restrict__ out0, int M) {
    __shared__ float Wl[32][128];  // 16.4 KB
    __shared__ float Al[64][36];   // 9.2 KB (stride 36: 16B-aligned, even banks)
    const int t = threadIdx.x;
    const int row0 = blockIdx.x * 64;
    const int tr = t >> 4;
    const int tc = t & 15;

    float acc[4][8];
#pragma unroll
    for (int i = 0; i < 4; ++i)
#pragma unroll
        for (int j = 0; j < 8; ++j) acc[i][j] = 0.0f;

    for (int kc = 0; kc < 4; ++kc) {
        __syncthreads();
#pragma unroll
        for (int rep = 0; rep < 4; ++rep) {
            int i = t + rep * 256;
            int k = i >> 5;
            int cq = i & 31;
            float4 v = *(const float4*)&W[(size_t)(kc * 32 + k) * HD + cq * 4];
            *(float4*)&Wl[k][cq * 4] = v;
        }
#pragma unroll
        for (int rep = 0; rep < 2; ++rep) {
            int i = t + rep * 256;
            int r = i >> 3;
            int kq = i & 7;
            int grow = row0 + r;
            float4 v = make_float4(0.f, 0.f, 0.f, 0.f);
            if (grow < M) v = *(const float4*)&A[(size_t)grow * HD + kc * 32 + kq * 4];
            *(float4*)&Al[r][kq * 4] = v;
        }
        __syncthreads();
#pragma unroll 2
        for (int k4 = 0; k4 < 32; k4 += 4) {
            float4 a4[4];
#pragma unroll
            for (int i = 0; i < 4; ++i) a4[i] = *(const float4*)&Al[tr * 4 + i][k4];
#pragma unroll
            for (int kk = 0; kk < 4; ++kk) {
                float4 b0 = *(const float4*)&Wl[k4 + kk][tc * 4];
                float4 b1 = *(const float4*)&Wl[k4 + kk][64 + tc * 4];
                float bv[8] = {b0.x, b0.y, b0.z, b0.w, b1.x, b1.y, b1.z, b1.w};
#pragma unroll
                for (int i = 0; i < 4; ++i) {
                    float av = ((const float*)&a4[i])[kk];
#pragma unroll
                    for (int j = 0; j < 8; ++j) acc[i][j] = fmaf(av, bv[j], acc[i][j]);
                }
            }
        }
    }

#pragma unroll
    for (int i = 0; i < 4; ++i) {
        int grow = row0 + tr * 4 + i;
        if (grow < M) {
            size_t base = (size_t)grow * HD;
            float4 o0, o1;
            if (MODE == 0) {
                o0.x = fmaxf(acc[i][0] + bias[tc * 4 + 0], 0.f);
                o0.y = fmaxf(acc[i][1] + bias[tc * 4 + 1], 0.f);
                o0.z = fmaxf(acc[i][2] + bias[tc * 4 + 2], 0.f);
                o0.w = fmaxf(acc[i][3] + bias[tc * 4 + 3], 0.f);
                o1.x = fmaxf(acc[i][4] + bias[64 + tc * 4 + 0], 0.f);
                o1.y = fmaxf(acc[i][5] + bias[64 + tc * 4 + 1], 0.f);
                o1.z = fmaxf(acc[i][6] + bias[64 + tc * 4 + 2], 0.f);
                o1.w = fmaxf(acc[i][7] + bias[64 + tc * 4 + 3], 0.f);
            } else {
                o0 = make_float4(acc[i][0], acc[i][1], acc[i][2], acc[i][3]);
                o1 = make_float4(acc[i][4], acc[i][5], acc[i][6], acc[i][7]);
            }
            *(float4*)&out0[base + tc * 4] = o0;
            *(float4*)&out0[base + 64 + tc * 4] = o1;
        }
    }
}

// ---------------- pull aggregation + BN + ReLU (one wave per node) --------
__global__ __launch_bounds__(256) void agg_kernel(const int* __restrict__ offsets,
                                                  const float2* __restrict__ csr,
                                                  const float* __restrict__ dinv,
                                                  const float* __restrict__ hw,
                                                  const float* __restrict__ bnA,
                                                  const float* __restrict__ bnB,
                                                  float* __restrict__ hout) {
    int w = (blockIdx.x * 256 + threadIdx.x) >> 6;
    int lane = threadIdx.x & 63;
    if (w >= NN) return;
    int c = lane * 2;
    int b0 = offsets[w];
    int b1 = offsets[w + 1];
    float dd = dinv[w];
    dd *= dd;
    float2 v = *(const float2*)&hw[(size_t)w * HD + c];
    float ax = dd * v.x, ay = dd * v.y;
    for (int j = b0; j < b1; ++j) {
        float2 sc = csr[j];
        int s = __float_as_int(sc.x);
        float cf = sc.y;
        float2 u = *(const float2*)&hw[(size_t)s * HD + c];
        ax = fmaf(cf, u.x, ax);
        ay = fmaf(cf, u.y, ay);
    }
    float rx = fmaxf(fmaf(ax, bnA[c], bnB[c]), 0.f);
    float ry = fmaxf(fmaf(ay, bnA[c + 1], bnB[c + 1]), 0.f);
    *(float2*)&hout[(size_t)w * HD + c] = make_float2(rx, ry);
}

// ---------------- segmented mean pool (batch sorted -> contiguous) --------
__global__ __launch_bounds__(256) void pool_kernel(const float* __restrict__ h,
                                                   const int* __restrict__ goff,
                                                   float* __restrict__ g) {
    int b = blockIdx.x;
    int t = threadIdx.x;
    int c = t & 127;
    int half = t >> 7;  // 0 or 1
    int i0 = goff[b], i1 = goff[b + 1];
    float acc = 0.f;
    for (int i = i0 + half; i < i1; i += 2) acc += h[(size_t)i * HD + c];
    __shared__ float sh[256];
    sh[t] = acc;
    __syncthreads();
    if (half == 0) {
        float s = sh[c] + sh[128 + c];
        float invc = 1.0f / fmaxf((float)(i1 - i0), 1.0f);
        g[(size_t)b * HD + c] = s * invc;
    }
}

// ---------------- per-graph MLP head ----------------
__global__ __launch_bounds__(64) void mlp_kernel(const float* __restrict__ g,
                                                 const float* __restrict__ fc1w,
                                                 const float* __restrict__ fc1b,
                                                 const float* __restrict__ fc2w,
                                                 const float* __restrict__ fc2b,
                                                 float* __restrict__ out) {
    __shared__ float gr[128];
    __shared__ float f1[64];
    int b = blockIdx.x, t = threadIdx.x;
    gr[t] = g[(size_t)b * HD + t];
    gr[t + 64] = g[(size_t)b * HD + 64 + t];
    __syncthreads();
    float acc = fc1b[t];
#pragma unroll 8
    for (int k = 0; k < 128; ++k) acc = fmaf(gr[k], fc1w[k * 64 + t], acc);
    f1[t] = fmaxf(acc, 0.f);
    __syncthreads();
    if (t < NC) {
        float a2 = fc2b[t];
#pragma unroll 8
        for (int k = 0; k < 64; ++k) a2 = fmaf(f1[k], fc2w[k * NC + t], a2);
        out[b * NC + t] = a2;
    }
    if (b == 0 && t == 63) out[NG * NC] = 0.0f;  // aux scalar output
}

// ---------------- launch ----------------
extern "C" void kernel_launch(void* const* d_in, const int* in_sizes, int n_in,
                              void* d_out, int out_size, void* d_ws, size_t ws_size,
                              hipStream_t stream) {
    const float* x      = (const float*)d_in[0];
    const int*   ei     = (const int*)d_in[1];
    const int*   batch  = (const int*)d_in[2];
    const float* w_in   = (const float*)d_in[3];
    const float* b_in   = (const float*)d_in[4];
    const float* conv_w = (const float*)d_in[5];
    const float* conv_b = (const float*)d_in[6];
    const float* gam    = (const float*)d_in[7];
    const float* bet    = (const float*)d_in[8];
    const float* mu     = (const float*)d_in[9];
    const float* var    = (const float*)d_in[10];
    const float* fc1w   = (const float*)d_in[11];
    const float* fc1b   = (const float*)d_in[12];
    const float* fc2w   = (const float*)d_in[13];
    const float* fc2b   = (const float*)d_in[14];
    float* out = (float*)d_out;

    size_t NH = (size_t)NN * HD;
    float* bufA = (float*)d_ws;               // h
    float* bufB = bufA + NH;                  // hw
    float* deg  = bufB + NH;
    float* dinv = deg + NN;
    float* bnA  = dinv + NN;                  // NL*HD
    float* bnB  = bnA + NL * HD;              // NL*HD
    float* g    = bnB + NL * HD;              // NG*HD
    int* offsets  = (int*)(g + (size_t)NG * HD);  // NN+1
    int* cursor   = offsets + NN + 1;         // NN
    int* loc      = cursor + NN;              // NN
    int* bsum     = loc + NN;                 // NB
    int* goff     = bsum + NB;                // NG+1
    float2* csr   = (float2*)(goff + NG + 1); // NE float2

    hipMemsetAsync(deg, 0, NN * sizeof(float), stream);

    deg_kernel<<<(NE + 255) / 256, 256, 0, stream>>>(ei, deg);
    dinv_kernel<<<(NN + 255) / 256, 256, 0, stream>>>(deg, dinv);
    scanA_kernel<<<NB, 256, 0, stream>>>(deg, loc, bsum);
    scanB_kernel<<<1, 512, 0, stream>>>(bsum);
    scanC_kernel<<<NB, 256, 0, stream>>>(loc, bsum, offsets, cursor);
    fill_kernel<<<(NE + 255) / 256, 256, 0, stream>>>(ei, dinv, cursor, csr);
    bnpre_kernel<<<NL, 128, 0, stream>>>(conv_b, gam, bet, mu, var, bnA, bnB);
    gboff_kernel<<<(NG + 64) / 64, 64, 0, stream>>>(batch, goff);

    int gblocks = (NN + 63) / 64;
    gemm128<0><<<gblocks, 256, 0, stream>>>(x, w_in, b_in, bufA, NN);

    for (int l = 0; l < NL; ++l) {
        gemm128<1><<<gblocks, 256, 0, stream>>>(bufA, conv_w + (size_t)l * HD * HD,
                                                nullptr, bufB, NN);
        agg_kernel<<<(NN * 64 + 255) / 256, 256, 0, stream>>>(
            offsets, csr, dinv, bufB, bnA + l * HD, bnB + l * HD, bufA);
    }

    pool_kernel<<<NG, 256, 0, stream>>>(bufA, goff, g);
    mlp_kernel<<<NG, 64, 0, stream>>>(g, fc1w, fc1b, fc2w, fc2b, out);
}

// Round 5
// 859.275 us; speedup vs baseline: 6.9409x; 1.4401x over previous
//
#include <hip/hip_runtime.h>
#include <hip/hip_fp16.h>
#include <cstdint>

#define NN 100000
#define NE 1600000
#define HD 128
#define NL 4
#define NC 12
#define NG 512
#define NB ((NN + 255) / 256)  // 391 scan blocks
#define BN_EPS 1e-5f

// ---------------- degree / normalization precompute ----------------

__global__ __launch_bounds__(256) void deg_kernel(const int* __restrict__ ei,
                                                  float* __restrict__ deg) {
    int e = blockIdx.x * 256 + threadIdx.x;
    if (e < NE) unsafeAtomicAdd(&deg[ei[NE + e]], 1.0f);
}

__global__ __launch_bounds__(256) void dinv_kernel(const float* __restrict__ deg,
                                                   float* __restrict__ dinv) {
    int i = blockIdx.x * 256 + threadIdx.x;
    if (i < NN) dinv[i] = rsqrtf(deg[i] + 1.0f);
}

// ---- parallel scan: A) per-block exclusive scan + block sums ----
__global__ __launch_bounds__(256) void scanA_kernel(const float* __restrict__ deg,
                                                    int* __restrict__ loc,
                                                    int* __restrict__ bsum) {
    __shared__ int sh[256];
    int t = threadIdx.x;
    int i = blockIdx.x * 256 + t;
    int v = (i < NN) ? (int)deg[i] : 0;
    sh[t] = v;
    __syncthreads();
    for (int off = 1; off < 256; off <<= 1) {
        int x = sh[t];
        int add = (t >= off) ? sh[t - off] : 0;
        __syncthreads();
        sh[t] = x + add;
        __syncthreads();
    }
    if (i < NN) loc[i] = sh[t] - v;  // exclusive within block
    if (t == 255) bsum[blockIdx.x] = sh[255];
}

// ---- B) scan the 391 block sums (one block) ----
__global__ __launch_bounds__(512) void scanB_kernel(int* __restrict__ bsum) {
    __shared__ int sh[512];
    int t = threadIdx.x;
    int v = (t < NB) ? bsum[t] : 0;
    sh[t] = v;
    __syncthreads();
    for (int off = 1; off < 512; off <<= 1) {
        int x = sh[t];
        int add = (t >= off) ? sh[t - off] : 0;
        __syncthreads();
        sh[t] = x + add;
        __syncthreads();
    }
    if (t < NB) bsum[t] = sh[t] - v;  // exclusive block prefix
}

// ---- C) combine -> offsets, cursor ----
__global__ __launch_bounds__(256) void scanC_kernel(const int* __restrict__ loc,
                                                    const int* __restrict__ bsum,
                                                    int* __restrict__ offsets,
                                                    int* __restrict__ cursor) {
    int i = blockIdx.x * 256 + threadIdx.x;
    if (i < NN) {
        int o = bsum[blockIdx.x] + loc[i];
        offsets[i] = o;
        cursor[i] = o;
    }
    if (i == 0) offsets[NN] = NE;
}

// fill CSR packed: csr[pos] = (bits(src), dinv[src]*dinv[dst])
__global__ __launch_bounds__(256) void fill_kernel(const int* __restrict__ ei,
                                                   const float* __restrict__ dinv,
                                                   int* __restrict__ cursor,
                                                   float2* __restrict__ csr) {
    int e = blockIdx.x * 256 + threadIdx.x;
    if (e < NE) {
        int s = ei[e];
        int d = ei[NE + e];
        int pos = atomicAdd(&cursor[d], 1);
        csr[pos] = make_float2(__int_as_float(s), dinv[s] * dinv[d]);
    }
}

// per-layer BN fold: val = acc*A + B
__global__ __launch_bounds__(128) void bnpre_kernel(const float* __restrict__ cb,
                                                    const float* __restrict__ gam,
                                                    const float* __restrict__ bet,
                                                    const float* __restrict__ mu,
                                                    const float* __restrict__ var,
                                                    float* __restrict__ bnA,
                                                    float* __restrict__ bnB) {
    int i = blockIdx.x * 128 + threadIdx.x;  // over NL*HD
    float a = gam[i] * rsqrtf(var[i] + BN_EPS);
    bnA[i] = a;
    bnB[i] = (cb[i] - mu[i]) * a + bet[i];
}

// graph boundaries: goff[g] = first node with batch >= g (batch is sorted)
__global__ __launch_bounds__(64) void gboff_kernel(const int* __restrict__ batch,
                                                   int* __restrict__ goff) {
    int g = blockIdx.x * 64 + threadIdx.x;
    if (g > NG) return;
    int lo = 0, hi = NN;
    while (lo < hi) {
        int mid = (lo + hi) >> 1;
        if (batch[mid] < g) lo = mid + 1; else hi = mid;
    }
    goff[g] = lo;
}

// ---------------- fp32 GEMM: [M,128] x [128,128] ----------------
// MODE 0: out = relu(acc + bias) -> float*   MODE 1: out = acc -> __half*
template <int MODE>
__global__ __launch_bounds__(256) void gemm128(const float* __restrict__ A,
                                               const float* __restrict__ W,
                                               const float* __restrict__ bias,
                                               void* __restrict__ out0v, int M) {
    __shared__ float Wl[32][128];  // 16.4 KB
    __shared__ float Al[64][36];   // 9.2 KB
    const int t = threadIdx.x;
    const int row0 = blockIdx.x * 64;
    const int tr = t >> 4;
    const int tc = t & 15;

    float acc[4][8];
#pragma unroll
    for (int i = 0; i < 4; ++i)
#pragma unroll
        for (int j = 0; j < 8; ++j) acc[i][j] = 0.0f;

    for (int kc = 0; kc < 4; ++kc) {
        __syncthreads();
#pragma unroll
        for (int rep = 0; rep < 4; ++rep) {
            int i = t + rep * 256;
            int k = i >> 5;
            int cq = i & 31;
            float4 v = *(const float4*)&W[(size_t)(kc * 32 + k) * HD + cq * 4];
            *(float4*)&Wl[k][cq * 4] = v;
        }
#pragma unroll
        for (int rep = 0; rep < 2; ++rep) {
            int i = t + rep * 256;
            int r = i >> 3;
            int kq = i & 7;
            int grow = row0 + r;
            float4 v = make_float4(0.f, 0.f, 0.f, 0.f);
            if (grow < M) v = *(const float4*)&A[(size_t)grow * HD + kc * 32 + kq * 4];
            *(float4*)&Al[r][kq * 4] = v;
        }
        __syncthreads();
#pragma unroll 2
        for (int k4 = 0; k4 < 32; k4 += 4) {
            float4 a4[4];
#pragma unroll
            for (int i = 0; i < 4; ++i) a4[i] = *(const float4*)&Al[tr * 4 + i][k4];
#pragma unroll
            for (int kk = 0; kk < 4; ++kk) {
                float4 b0 = *(const float4*)&Wl[k4 + kk][tc * 4];
                float4 b1 = *(const float4*)&Wl[k4 + kk][64 + tc * 4];
                float bv[8] = {b0.x, b0.y, b0.z, b0.w, b1.x, b1.y, b1.z, b1.w};
#pragma unroll
                for (int i = 0; i < 4; ++i) {
                    float av = ((const float*)&a4[i])[kk];
#pragma unroll
                    for (int j = 0; j < 8; ++j) acc[i][j] = fmaf(av, bv[j], acc[i][j]);
                }
            }
        }
    }

#pragma unroll
    for (int i = 0; i < 4; ++i) {
        int grow = row0 + tr * 4 + i;
        if (grow < M) {
            size_t base = (size_t)grow * HD;
            if (MODE == 0) {
                float* out0 = (float*)out0v;
                float4 o0, o1;
                o0.x = fmaxf(acc[i][0] + bias[tc * 4 + 0], 0.f);
                o0.y = fmaxf(acc[i][1] + bias[tc * 4 + 1], 0.f);
                o0.z = fmaxf(acc[i][2] + bias[tc * 4 + 2], 0.f);
                o0.w = fmaxf(acc[i][3] + bias[tc * 4 + 3], 0.f);
                o1.x = fmaxf(acc[i][4] + bias[64 + tc * 4 + 0], 0.f);
                o1.y = fmaxf(acc[i][5] + bias[64 + tc * 4 + 1], 0.f);
                o1.z = fmaxf(acc[i][6] + bias[64 + tc * 4 + 2], 0.f);
                o1.w = fmaxf(acc[i][7] + bias[64 + tc * 4 + 3], 0.f);
                *(float4*)&out0[base + tc * 4] = o0;
                *(float4*)&out0[base + 64 + tc * 4] = o1;
            } else {
                __half* out0 = (__half*)out0v;
                __half2 a01 = __floats2half2_rn(acc[i][0], acc[i][1]);
                __half2 a23 = __floats2half2_rn(acc[i][2], acc[i][3]);
                __half2 a45 = __floats2half2_rn(acc[i][4], acc[i][5]);
                __half2 a67 = __floats2half2_rn(acc[i][6], acc[i][7]);
                uint2 lo = make_uint2(*(uint32_t*)&a01, *(uint32_t*)&a23);
                uint2 hi = make_uint2(*(uint32_t*)&a45, *(uint32_t*)&a67);
                *(uint2*)&out0[base + tc * 4] = lo;
                *(uint2*)&out0[base + 64 + tc * 4] = hi;
            }
        }
    }
}

// ------- pull aggregation + BN + ReLU (one wave/node, fp16 gather) -------
__global__ __launch_bounds__(256) void agg_kernel(const int* __restrict__ offsets,
                                                  const float2* __restrict__ csr,
                                                  const float* __restrict__ dinv,
                                                  const __half2* __restrict__ hw2,
                                                  const float* __restrict__ bnA,
                                                  const float* __restrict__ bnB,
                                                  float* __restrict__ hout) {
    int w = (blockIdx.x * 256 + threadIdx.x) >> 6;
    int lane = threadIdx.x & 63;
    if (w >= NN) return;
    int c = lane * 2;
    int b0 = offsets[w];
    int b1 = offsets[w + 1];
    float dd = dinv[w];
    dd *= dd;
    float2 v = __half22float2(hw2[(size_t)w * 64 + lane]);
    float ax = dd * v.x, ay = dd * v.y;
    int j = b0;
    for (; j + 4 <= b1; j += 4) {
        float2 sc0 = csr[j + 0];
        float2 sc1 = csr[j + 1];
        float2 sc2 = csr[j + 2];
        float2 sc3 = csr[j + 3];
        __half2 u0 = hw2[(size_t)__float_as_int(sc0.x) * 64 + lane];
        __half2 u1 = hw2[(size_t)__float_as_int(sc1.x) * 64 + lane];
        __half2 u2 = hw2[(size_t)__float_as_int(sc2.x) * 64 + lane];
        __half2 u3 = hw2[(size_t)__float_as_int(sc3.x) * 64 + lane];
        float2 f0 = __half22float2(u0);
        float2 f1 = __half22float2(u1);
        float2 f2 = __half22float2(u2);
        float2 f3 = __half22float2(u3);
        ax = fmaf(sc0.y, f0.x, ax);
        ay = fmaf(sc0.y, f0.y, ay);
        ax = fmaf(sc1.y, f1.x, ax);
        ay = fmaf(sc1.y, f1.y, ay);
        ax = fmaf(sc2.y, f2.x, ax);
        ay = fmaf(sc2.y, f2.y, ay);
        ax = fmaf(sc3.y, f3.x, ax);
        ay = fmaf(sc3.y, f3.y, ay);
    }
    for (; j < b1; ++j) {
        float2 sc = csr[j];
        float2 u = __half22float2(hw2[(size_t)__float_as_int(sc.x) * 64 + lane]);
        ax = fmaf(sc.y, u.x, ax);
        ay = fmaf(sc.y, u.y, ay);
    }
    float rx = fmaxf(fmaf(ax, bnA[c], bnB[c]), 0.f);
    float ry = fmaxf(fmaf(ay, bnA[c + 1], bnB[c + 1]), 0.f);
    *(float2*)&hout[(size_t)w * HD + c] = make_float2(rx, ry);
}

// ---------------- segmented mean pool (batch sorted -> contiguous) --------
__global__ __launch_bounds__(256) void pool_kernel(const float* __restrict__ h,
                                                   const int* __restrict__ goff,
                                                   float* __restrict__ g) {
    int b = blockIdx.x;
    int t = threadIdx.x;
    int c = t & 127;
    int half = t >> 7;  // 0 or 1
    int i0 = goff[b], i1 = goff[b + 1];
    float acc = 0.f;
    for (int i = i0 + half; i < i1; i += 2) acc += h[(size_t)i * HD + c];
    __shared__ float sh[256];
    sh[t] = acc;
    __syncthreads();
    if (half == 0) {
        float s = sh[c] + sh[128 + c];
        float invc = 1.0f / fmaxf((float)(i1 - i0), 1.0f);
        g[(size_t)b * HD + c] = s * invc;
    }
}

// ---------------- per-graph MLP head ----------------
__global__ __launch_bounds__(64) void mlp_kernel(const float* __restrict__ g,
                                                 const float* __restrict__ fc1w,
                                                 const float* __restrict__ fc1b,
                                                 const float* __restrict__ fc2w,
                                                 const float* __restrict__ fc2b,
                                                 float* __restrict__ out) {
    __shared__ float gr[128];
    __shared__ float f1[64];
    int b = blockIdx.x, t = threadIdx.x;
    gr[t] = g[(size_t)b * HD + t];
    gr[t + 64] = g[(size_t)b * HD + 64 + t];
    __syncthreads();
    float acc = fc1b[t];
#pragma unroll 8
    for (int k = 0; k < 128; ++k) acc = fmaf(gr[k], fc1w[k * 64 + t], acc);
    f1[t] = fmaxf(acc, 0.f);
    __syncthreads();
    if (t < NC) {
        float a2 = fc2b[t];
#pragma unroll 8
        for (int k = 0; k < 64; ++k) a2 = fmaf(f1[k], fc2w[k * NC + t], a2);
        out[b * NC + t] = a2;
    }
    if (b == 0 && t == 63) out[NG * NC] = 0.0f;  // aux scalar output
}

// ---------------- launch ----------------
extern "C" void kernel_launch(void* const* d_in, const int* in_sizes, int n_in,
                              void* d_out, int out_size, void* d_ws, size_t ws_size,
                              hipStream_t stream) {
    const float* x      = (const float*)d_in[0];
    const int*   ei     = (const int*)d_in[1];
    const int*   batch  = (const int*)d_in[2];
    const float* w_in   = (const float*)d_in[3];
    const float* b_in   = (const float*)d_in[4];
    const float* conv_w = (const float*)d_in[5];
    const float* conv_b = (const float*)d_in[6];
    const float* gam    = (const float*)d_in[7];
    const float* bet    = (const float*)d_in[8];
    const float* mu     = (const float*)d_in[9];
    const float* var    = (const float*)d_in[10];
    const float* fc1w   = (const float*)d_in[11];
    const float* fc1b   = (const float*)d_in[12];
    const float* fc2w   = (const float*)d_in[13];
    const float* fc2b   = (const float*)d_in[14];
    float* out = (float*)d_out;

    size_t NH = (size_t)NN * HD;
    float* bufA = (float*)d_ws;                   // h (fp32)
    __half2* hw2 = (__half2*)(bufA + NH);         // hw (fp16), NN*64 half2
    float* deg  = (float*)(hw2 + (size_t)NN * 64);
    float* dinv = deg + NN;
    float* bnA  = dinv + NN;                      // NL*HD
    float* bnB  = bnA + NL * HD;                  // NL*HD
    float* g    = bnB + NL * HD;                  // NG*HD
    int* offsets  = (int*)(g + (size_t)NG * HD);  // NN+1
    int* cursor   = offsets + NN + 1;             // NN
    int* loc      = cursor + NN;                  // NN
    int* bsum     = loc + NN;                     // NB
    int* goff     = bsum + NB;                    // NG+1
    float2* csr   = (float2*)(goff + NG + 1);     // NE float2

    hipMemsetAsync(deg, 0, NN * sizeof(float), stream);

    deg_kernel<<<(NE + 255) / 256, 256, 0, stream>>>(ei, deg);
    dinv_kernel<<<(NN + 255) / 256, 256, 0, stream>>>(deg, dinv);
    scanA_kernel<<<NB, 256, 0, stream>>>(deg, loc, bsum);
    scanB_kernel<<<1, 512, 0, stream>>>(bsum);
    scanC_kernel<<<NB, 256, 0, stream>>>(loc, bsum, offsets, cursor);
    fill_kernel<<<(NE + 255) / 256, 256, 0, stream>>>(ei, dinv, cursor, csr);
    bnpre_kernel<<<NL, 128, 0, stream>>>(conv_b, gam, bet, mu, var, bnA, bnB);
    gboff_kernel<<<(NG + 64) / 64, 64, 0, stream>>>(batch, goff);

    int gblocks = (NN + 63) / 64;
    gemm128<0><<<gblocks, 256, 0, stream>>>(x, w_in, b_in, bufA, NN);

    for (int l = 0; l < NL; ++l) {
        gemm128<1><<<gblocks, 256, 0, stream>>>(bufA, conv_w + (size_t)l * HD * HD,
                                                nullptr, hw2, NN);
        agg_kernel<<<(NN * 64 + 255) / 256, 256, 0, stream>>>(
            offsets, csr, dinv, hw2, bnA + l * HD, bnB + l * HD, bufA);
    }

    pool_kernel<<<NG, 256, 0, stream>>>(bufA, goff, g);
    mlp_kernel<<<NG, 64, 0, stream>>>(g, fc1w, fc1b, fc2w, fc2b, out);
}

// Round 6
// 782.568 us; speedup vs baseline: 7.6212x; 1.0980x over previous
//
#include <hip/hip_runtime.h>
#include <cstdint>

#define NN 100000
#define NE 1600000
#define HD 128
#define NL 4
#define NC 12
#define NG 512
#define NB ((NN + 255) / 256)   // 391
#define NEB (NE / 256)          // 6250
#define NSH 8
#define BN_EPS 1e-5f

typedef _Float16 f16;
typedef _Float16 f16x2 __attribute__((ext_vector_type(2)));
typedef _Float16 f16x8 __attribute__((ext_vector_type(8)));
typedef float f32x4 __attribute__((ext_vector_type(4)));

// ---------------- sharded degree histogram ----------------
__global__ __launch_bounds__(256) void degS_kernel(const int* __restrict__ ei,
                                                   unsigned* __restrict__ degS) {
    int e = blockIdx.x * 256 + threadIdx.x;  // grid exact
    int sh = blockIdx.x & (NSH - 1);
    atomicAdd(&degS[(size_t)sh * NN + ei[NE + e]], 1u);
}

__global__ __launch_bounds__(256) void degsum_kernel(const unsigned* __restrict__ degS,
                                                     int* __restrict__ deg) {
    int i = blockIdx.x * 256 + threadIdx.x;
    if (i < NN) {
        unsigned s = 0;
#pragma unroll
        for (int sh = 0; sh < NSH; ++sh) s += degS[(size_t)sh * NN + i];
        deg[i] = (int)s;
    }
}

__global__ __launch_bounds__(256) void dinv_kernel(const int* __restrict__ deg,
                                                   float* __restrict__ dinv) {
    int i = blockIdx.x * 256 + threadIdx.x;
    if (i < NN) dinv[i] = rsqrtf((float)deg[i] + 1.0f);
}

// ---- parallel scan: A) per-block exclusive scan + block sums ----
__global__ __launch_bounds__(256) void scanA_kernel(const int* __restrict__ deg,
                                                    int* __restrict__ loc,
                                                    int* __restrict__ bsum) {
    __shared__ int sh[256];
    int t = threadIdx.x;
    int i = blockIdx.x * 256 + t;
    int v = (i < NN) ? deg[i] : 0;
    sh[t] = v;
    __syncthreads();
    for (int off = 1; off < 256; off <<= 1) {
        int x = sh[t];
        int add = (t >= off) ? sh[t - off] : 0;
        __syncthreads();
        sh[t] = x + add;
        __syncthreads();
    }
    if (i < NN) loc[i] = sh[t] - v;
    if (t == 255) bsum[blockIdx.x] = sh[255];
}

__global__ __launch_bounds__(512) void scanB_kernel(int* __restrict__ bsum) {
    __shared__ int sh[512];
    int t = threadIdx.x;
    int v = (t < NB) ? bsum[t] : 0;
    sh[t] = v;
    __syncthreads();
    for (int off = 1; off < 512; off <<= 1) {
        int x = sh[t];
        int add = (t >= off) ? sh[t - off] : 0;
        __syncthreads();
        sh[t] = x + add;
        __syncthreads();
    }
    if (t < NB) bsum[t] = sh[t] - v;
}

__global__ __launch_bounds__(256) void scanC_kernel(const int* __restrict__ loc,
                                                    const int* __restrict__ bsum,
                                                    int* __restrict__ offsets) {
    int i = blockIdx.x * 256 + threadIdx.x;
    if (i < NN) offsets[i] = bsum[blockIdx.x] + loc[i];
    if (i == 0) offsets[NN] = NE;
}

// per-node per-shard cursor init
__global__ __launch_bounds__(256) void cursorS_kernel(const int* __restrict__ offsets,
                                                      const unsigned* __restrict__ degS,
                                                      unsigned* __restrict__ cursorS) {
    int i = blockIdx.x * 256 + threadIdx.x;
    if (i < NN) {
        int base = offsets[i];
#pragma unroll
        for (int sh = 0; sh < NSH; ++sh) {
            cursorS[(size_t)sh * NN + i] = (unsigned)base;
            base += (int)degS[(size_t)sh * NN + i];
        }
    }
}

// fill CSR packed (sharded cursors; same edge->shard map as degS_kernel)
__global__ __launch_bounds__(256) void fillS_kernel(const int* __restrict__ ei,
                                                    const float* __restrict__ dinv,
                                                    unsigned* __restrict__ cursorS,
                                                    float2* __restrict__ csr) {
    int e = blockIdx.x * 256 + threadIdx.x;
    int sh = blockIdx.x & (NSH - 1);
    int s = ei[e];
    int d = ei[NE + e];
    unsigned pos = atomicAdd(&cursorS[(size_t)sh * NN + d], 1u);
    csr[pos] = make_float2(__int_as_float(s), dinv[s] * dinv[d]);
}

// per-layer BN fold: val = acc*A + B
__global__ __launch_bounds__(128) void bnpre_kernel(const float* __restrict__ cb,
                                                    const float* __restrict__ gam,
                                                    const float* __restrict__ bet,
                                                    const float* __restrict__ mu,
                                                    const float* __restrict__ var,
                                                    float* __restrict__ bnA,
                                                    float* __restrict__ bnB) {
    int i = blockIdx.x * 128 + threadIdx.x;
    float a = gam[i] * rsqrtf(var[i] + BN_EPS);
    bnA[i] = a;
    bnB[i] = (cb[i] - mu[i]) * a + bet[i];
}

// graph boundaries
__global__ __launch_bounds__(64) void gboff_kernel(const int* __restrict__ batch,
                                                   int* __restrict__ goff) {
    int g = blockIdx.x * 64 + threadIdx.x;
    if (g > NG) return;
    int lo = 0, hi = NN;
    while (lo < hi) {
        int mid = (lo + hi) >> 1;
        if (batch[mid] < g) lo = mid + 1; else hi = mid;
    }
    goff[g] = lo;
}

// weights: fp32 [k][n] -> fp16 transposed [n][k] (5 matrices)
__global__ __launch_bounds__(128) void wconv_kernel(const float* __restrict__ w_in,
                                                    const float* __restrict__ conv_w,
                                                    f16* __restrict__ Wt) {
    int m = blockIdx.x >> 7;       // 0..4
    int k = blockIdx.x & 127;
    int n = threadIdx.x;
    const float* src = (m == 0) ? w_in : conv_w + (size_t)(m - 1) * HD * HD;
    Wt[((size_t)m * HD + n) * HD + k] = (f16)src[k * HD + n];
}

// x fp32 -> fp16
__global__ __launch_bounds__(256) void xconv_kernel(const float* __restrict__ x,
                                                    f16* __restrict__ xh) {
    int i = blockIdx.x * 256 + threadIdx.x;  // 1.6M threads, 8 elems each
    size_t b = (size_t)i * 8;
    float4 v0 = *(const float4*)&x[b];
    float4 v1 = *(const float4*)&x[b + 4];
    f16x8 o = {(f16)v0.x, (f16)v0.y, (f16)v0.z, (f16)v0.w,
               (f16)v1.x, (f16)v1.y, (f16)v1.z, (f16)v1.w};
    *(f16x8*)&xh[b] = o;
}

// ---------------- MFMA GEMM: [NN,128](f16) x Wt[n][k](f16) -> f16 -------
// MODE 0: out = relu(acc + bias)   MODE 1: out = acc
template <int MODE>
__global__ __launch_bounds__(256) void gemm_mfma(const f16* __restrict__ A,
                                                 const f16* __restrict__ Wt,
                                                 const float* __restrict__ bias,
                                                 f16* __restrict__ out) {
    const int l = threadIdx.x & 63;
    const int w = threadIdx.x >> 6;
    const int row0 = blockIdx.x * 64 + w * 16;
    const int l15 = l & 15;
    const int kg = (l >> 4) * 8;
    int ar = row0 + l15;
    if (ar >= NN) ar = NN - 1;
    const f16* Arow = A + (size_t)ar * HD + kg;
    const f16* Wb = Wt + (size_t)l15 * HD + kg;
    f32x4 acc[8];
    const f32x4 z = {0.f, 0.f, 0.f, 0.f};
#pragma unroll
    for (int t = 0; t < 8; ++t) acc[t] = z;
#pragma unroll
    for (int ks = 0; ks < 4; ++ks) {
        f16x8 a = *(const f16x8*)(Arow + ks * 32);
#pragma unroll
        for (int t = 0; t < 8; ++t) {
            f16x8 b = *(const f16x8*)(Wb + (size_t)t * 16 * HD + ks * 32);
            acc[t] = __builtin_amdgcn_mfma_f32_16x16x32_f16(a, b, acc[t], 0, 0, 0);
        }
    }
    const int orow = row0 + (l >> 4) * 4;
#pragma unroll
    for (int r = 0; r < 4; ++r) {
        int gr = orow + r;
        if (gr < NN) {
            f16* op = out + (size_t)gr * HD + l15;
#pragma unroll
            for (int t = 0; t < 8; ++t) {
                float v = acc[t][r];
                if (MODE == 0) v = fmaxf(v + bias[t * 16 + l15], 0.f);
                op[t * 16] = (f16)v;
            }
        }
    }
}

// ------- pull aggregation + BN + ReLU (one wave/node, fp16 gather) -------
__global__ __launch_bounds__(256) void agg_kernel(const int* __restrict__ offsets,
                                                  const float2* __restrict__ csr,
                                                  const float* __restrict__ dinv,
                                                  const f16x2* __restrict__ hw2,
                                                  const float* __restrict__ bnA,
                                                  const float* __restrict__ bnB,
                                                  f16x2* __restrict__ hout) {
    int w = (blockIdx.x * 256 + threadIdx.x) >> 6;
    int lane = threadIdx.x & 63;
    if (w >= NN) return;
    int c = lane * 2;
    int b0 = offsets[w];
    int b1 = offsets[w + 1];
    float dd = dinv[w];
    dd *= dd;
    f16x2 v = hw2[(size_t)w * 64 + lane];
    float ax = dd * (float)v.x, ay = dd * (float)v.y;
    int j = b0;
    for (; j + 4 <= b1; j += 4) {
        float2 sc0 = csr[j + 0];
        float2 sc1 = csr[j + 1];
        float2 sc2 = csr[j + 2];
        float2 sc3 = csr[j + 3];
        f16x2 u0 = hw2[(size_t)__float_as_int(sc0.x) * 64 + lane];
        f16x2 u1 = hw2[(size_t)__float_as_int(sc1.x) * 64 + lane];
        f16x2 u2 = hw2[(size_t)__float_as_int(sc2.x) * 64 + lane];
        f16x2 u3 = hw2[(size_t)__float_as_int(sc3.x) * 64 + lane];
        ax = fmaf(sc0.y, (float)u0.x, ax);
        ay = fmaf(sc0.y, (float)u0.y, ay);
        ax = fmaf(sc1.y, (float)u1.x, ax);
        ay = fmaf(sc1.y, (float)u1.y, ay);
        ax = fmaf(sc2.y, (float)u2.x, ax);
        ay = fmaf(sc2.y, (float)u2.y, ay);
        ax = fmaf(sc3.y, (float)u3.x, ax);
        ay = fmaf(sc3.y, (float)u3.y, ay);
    }
    for (; j < b1; ++j) {
        float2 sc = csr[j];
        f16x2 u = hw2[(size_t)__float_as_int(sc.x) * 64 + lane];
        ax = fmaf(sc.y, (float)u.x, ax);
        ay = fmaf(sc.y, (float)u.y, ay);
    }
    float rx = fmaxf(fmaf(ax, bnA[c], bnB[c]), 0.f);
    float ry = fmaxf(fmaf(ay, bnA[c + 1], bnB[c + 1]), 0.f);
    f16x2 o = {(f16)rx, (f16)ry};
    hout[(size_t)w * 64 + lane] = o;
}

// ---------------- segmented mean pool (fp16 input) ----------------
__global__ __launch_bounds__(256) void pool_kernel(const f16x2* __restrict__ h2,
                                                   const int* __restrict__ goff,
                                                   float* __restrict__ g) {
    int b = blockIdx.x, t = threadIdx.x;
    int p = t & 63, q = t >> 6;
    int i0 = goff[b], i1 = goff[b + 1];
    float sx = 0.f, sy = 0.f;
    for (int i = i0 + q; i < i1; i += 4) {
        f16x2 v = h2[(size_t)i * 64 + p];
        sx += (float)v.x;
        sy += (float)v.y;
    }
    __shared__ float shx[4][64], shy[4][64];
    shx[q][p] = sx;
    shy[q][p] = sy;
    __syncthreads();
    if (q == 0) {
        float fx = shx[0][p] + shx[1][p] + shx[2][p] + shx[3][p];
        float fy = shy[0][p] + shy[1][p] + shy[2][p] + shy[3][p];
        float invc = 1.0f / fmaxf((float)(i1 - i0), 1.0f);
        *(float2*)&g[(size_t)b * HD + p * 2] = make_float2(fx * invc, fy * invc);
    }
}

// ---------------- per-graph MLP head ----------------
__global__ __launch_bounds__(64) void mlp_kernel(const float* __restrict__ g,
                                                 const float* __restrict__ fc1w,
                                                 const float* __restrict__ fc1b,
                                                 const float* __restrict__ fc2w,
                                                 const float* __restrict__ fc2b,
                                                 float* __restrict__ out) {
    __shared__ float gr[128];
    __shared__ float f1[64];
    int b = blockIdx.x, t = threadIdx.x;
    gr[t] = g[(size_t)b * HD + t];
    gr[t + 64] = g[(size_t)b * HD + 64 + t];
    __syncthreads();
    float acc = fc1b[t];
#pragma unroll 8
    for (int k = 0; k < 128; ++k) acc = fmaf(gr[k], fc1w[k * 64 + t], acc);
    f1[t] = fmaxf(acc, 0.f);
    __syncthreads();
    if (t < NC) {
        float a2 = fc2b[t];
#pragma unroll 8
        for (int k = 0; k < 64; ++k) a2 = fmaf(f1[k], fc2w[k * NC + t], a2);
        out[b * NC + t] = a2;
    }
    if (b == 0 && t == 63) out[NG * NC] = 0.0f;  // aux scalar output
}

// ---------------- launch ----------------
extern "C" void kernel_launch(void* const* d_in, const int* in_sizes, int n_in,
                              void* d_out, int out_size, void* d_ws, size_t ws_size,
                              hipStream_t stream) {
    const float* x      = (const float*)d_in[0];
    const int*   ei     = (const int*)d_in[1];
    const int*   batch  = (const int*)d_in[2];
    const float* w_in   = (const float*)d_in[3];
    const float* b_in   = (const float*)d_in[4];
    const float* conv_w = (const float*)d_in[5];
    const float* conv_b = (const float*)d_in[6];
    const float* gam    = (const float*)d_in[7];
    const float* bet    = (const float*)d_in[8];
    const float* mu     = (const float*)d_in[9];
    const float* var    = (const float*)d_in[10];
    const float* fc1w   = (const float*)d_in[11];
    const float* fc1b   = (const float*)d_in[12];
    const float* fc2w   = (const float*)d_in[13];
    const float* fc2b   = (const float*)d_in[14];
    float* out = (float*)d_out;

    char* p = (char*)d_ws;
    auto alloc = [&](size_t bytes) -> void* {
        void* r = (void*)p;
        p += (bytes + 255) & ~(size_t)255;
        return r;
    };
    size_t NH = (size_t)NN * HD;
    f16* xh       = (f16*)alloc(NH * 2);
    f16* h        = (f16*)alloc(NH * 2);
    f16* hw       = (f16*)alloc(NH * 2);
    f16* Wt       = (f16*)alloc((size_t)5 * HD * HD * 2);
    float2* csr   = (float2*)alloc((size_t)NE * 8);
    int* deg      = (int*)alloc(NN * 4);
    float* dinv   = (float*)alloc(NN * 4);
    float* bnA    = (float*)alloc(NL * HD * 4);
    float* bnB    = (float*)alloc(NL * HD * 4);
    float* g      = (float*)alloc(NG * HD * 4);
    int* offsets  = (int*)alloc((NN + 1) * 4);
    int* loc      = (int*)alloc(NN * 4);
    int* bsum     = (int*)alloc(NB * 4);
    int* goff     = (int*)alloc((NG + 1) * 4);
    unsigned* degS    = (unsigned*)alloc((size_t)NSH * NN * 4);
    unsigned* cursorS = (unsigned*)alloc((size_t)NSH * NN * 4);

    hipMemsetAsync(degS, 0, (size_t)NSH * NN * 4, stream);

    degS_kernel<<<NEB, 256, 0, stream>>>(ei, degS);
    degsum_kernel<<<NB, 256, 0, stream>>>(degS, deg);
    dinv_kernel<<<NB, 256, 0, stream>>>(deg, dinv);
    scanA_kernel<<<NB, 256, 0, stream>>>(deg, loc, bsum);
    scanB_kernel<<<1, 512, 0, stream>>>(bsum);
    scanC_kernel<<<NB, 256, 0, stream>>>(loc, bsum, offsets);
    cursorS_kernel<<<NB, 256, 0, stream>>>(offsets, degS, cursorS);
    fillS_kernel<<<NEB, 256, 0, stream>>>(ei, dinv, cursorS, csr);
    bnpre_kernel<<<NL, 128, 0, stream>>>(conv_b, gam, bet, mu, var, bnA, bnB);
    gboff_kernel<<<(NG + 64) / 64, 64, 0, stream>>>(batch, goff);
    wconv_kernel<<<5 * 128, 128, 0, stream>>>(w_in, conv_w, Wt);
    xconv_kernel<<<NEB, 256, 0, stream>>>(x, xh);  // 12.8M elems / 8 / 256

    int gblocks = (NN + 63) / 64;
    gemm_mfma<0><<<gblocks, 256, 0, stream>>>(xh, Wt, b_in, h);

    for (int l = 0; l < NL; ++l) {
        gemm_mfma<1><<<gblocks, 256, 0, stream>>>(h, Wt + (size_t)(l + 1) * HD * HD,
                                                  nullptr, hw);
        agg_kernel<<<(NN * 64 + 255) / 256, 256, 0, stream>>>(
            offsets, csr, dinv, (const f16x2*)hw, bnA + l * HD, bnB + l * HD,
            (f16x2*)h);
    }

    pool_kernel<<<NG, 256, 0, stream>>>((const f16x2*)h, goff, g);
    mlp_kernel<<<NG, 64, 0, stream>>>(g, fc1w, fc1b, fc2w, fc2b, out);
}